// Round 17
// baseline (680.817 us; speedup 1.0000x reference)
//
#include <hip/hip_runtime.h>

#define N_ATOMS 100000
#define N_PAIRS 1600000
#define F_A 75
#define F_P 14
#define H 50

#define PROJ_BLOCKS (N_ATOMS / 32)   // 3125
#define SEG_BLOCKS  (N_ATOMS / 4)    // 25000
#define PO_BLOCKS   1024             // x8 waves = 8192 wave-slots (same as before)
#define AOUT_BLOCKS 1563             // 64 atoms/block, guarded tail

typedef float f32x2 __attribute__((ext_vector_type(2)));
typedef float f32x4 __attribute__((ext_vector_type(4)));
typedef short bf16x8 __attribute__((ext_vector_type(8)));

__device__ inline unsigned short f2bf(float f) {
    unsigned u = __float_as_uint(f);
    u += 0x7fffu + ((u >> 16) & 1u);
    return (unsigned short)(u >> 16);
}
__device__ inline float bfu(unsigned u, int hi) {
    return __uint_as_float(hi ? (u & 0xffff0000u) : (u << 16));
}

// ---------------- kernel 0: row_start[a] = lower_bound(split, a) ----------------
__global__ __launch_bounds__(256) void k_row_starts(
    const int* __restrict__ split, int* __restrict__ row_start)
{
    int p = blockIdx.x * 256 + threadIdx.x;
    if (p >= N_PAIRS) return;
    int s = split[p];
    int sp = (p == 0) ? -1 : split[p - 1];
    for (int a = sp + 1; a <= s; ++a) row_start[a] = p;
    if (p == N_PAIRS - 1)
        for (int a = s + 1; a <= N_ATOMS; ++a) row_start[a] = N_PAIRS;
}

// ================= stage 1 (fat, ZERO LDS): atom_proj || pa_segsum =================
__global__ __launch_bounds__(256) void k_stage1(
    const float* __restrict__ af, const float* __restrict__ W_AA,
    const float* __restrict__ b_AA, const float* __restrict__ W_AP,
    const float* __restrict__ b_AP,
    const float* __restrict__ pf, const int* __restrict__ row_start,
    const float* __restrict__ W_PA, const float* __restrict__ b_PA,
    float* __restrict__ AA, unsigned short* __restrict__ X,
    float* __restrict__ PA)
{
    const int wave = __builtin_amdgcn_readfirstlane(threadIdx.x >> 6);
    const int lane = threadIdx.x & 63;
    const int h = lane < H ? lane : 0;

    if (blockIdx.x < PROJ_BLOCKS) {
        const int base = blockIdx.x * 32 + wave * 8;
        const float bAA = b_AA[h];
        const float bAP = (lane < H) ? b_AP[lane] : 0.f;

        float aa[8], x1[8], x2[8];
        #pragma unroll
        for (int a = 0; a < 8; ++a) { aa[a] = bAA; x1[a] = 0.f; x2[a] = 0.f; }

        // chunk-4 column loop: af rows fetched as wave-uniform dwordx4
        for (int c0 = 0; c0 < 72; c0 += 4) {
            f32x4 fv[8];
            #pragma unroll
            for (int a = 0; a < 8; ++a)
                fv[a] = *(const f32x4*)(af + (size_t)(base + a) * F_A + c0);
            #pragma unroll
            for (int cc = 0; cc < 4; ++cc) {
                int c = c0 + cc;
                float waa = W_AA[c * H + h];
                float w1  = W_AP[c * H + h];
                float w2  = W_AP[(F_A + c) * H + h];
                #pragma unroll
                for (int a = 0; a < 8; ++a) {
                    float f = fv[a][cc];
                    aa[a] = fmaf(f, waa, aa[a]);
                    x1[a] = fmaf(f, w1, x1[a]);
                    x2[a] = fmaf(f, w2, x2[a]);
                }
            }
        }
        #pragma unroll
        for (int c = 72; c < F_A; ++c) {   // tail 3 columns
            float waa = W_AA[c * H + h];
            float w1  = W_AP[c * H + h];
            float w2  = W_AP[(F_A + c) * H + h];
            #pragma unroll
            for (int a = 0; a < 8; ++a) {
                float f = af[(size_t)(base + a) * F_A + c];
                aa[a] = fmaf(f, waa, aa[a]);
                x1[a] = fmaf(f, w1, x1[a]);
                x2[a] = fmaf(f, w2, x2[a]);
            }
        }
        #pragma unroll
        for (int a = 0; a < 8; ++a) {
            int atom = base + a;
            if (lane < H) AA[(size_t)atom * H + lane] = fmaxf(aa[a], 0.f);
            unsigned short v1 = (lane < H) ? f2bf(x1[a] + bAP) : (unsigned short)0;
            unsigned short v2 = (lane < H) ? f2bf(x2[a]) : (unsigned short)0;
            unsigned short* Xrow = X + (size_t)atom * 128;
            Xrow[lane]      = v1;
            Xrow[64 + lane] = v2;
        }
    } else {
        const int atom = (blockIdx.x - PROJ_BLOCKS) * 4 + wave;

        float w[F_P];
        #pragma unroll
        for (int c = 0; c < F_P; ++c) w[c] = W_PA[c * H + h];
        const float bias = b_PA[h];

        const int start = row_start[atom];
        const int end   = row_start[atom + 1];

        float acc = 0.f;
        int p = start;
        for (; p + 4 <= end; p += 4) {
            f32x2 v[4][7];
            #pragma unroll
            for (int r = 0; r < 4; ++r) {
                const f32x2* src = (const f32x2*)(pf + (size_t)(p + r) * F_P);
                #pragma unroll
                for (int c = 0; c < 7; ++c) v[r][c] = __builtin_nontemporal_load(src + c);
            }
            #pragma unroll
            for (int r = 0; r < 4; ++r) {
                float s0 = bias;
                #pragma unroll
                for (int c = 0; c < 7; ++c) {
                    s0 = fmaf(v[r][c].x, w[2*c], s0);
                    s0 = fmaf(v[r][c].y, w[2*c+1], s0);
                }
                acc += fmaxf(s0, 0.f);
            }
        }
        for (; p < end; ++p) {
            const f32x2* src = (const f32x2*)(pf + (size_t)p * F_P);
            float s0 = bias;
            #pragma unroll
            for (int c = 0; c < 7; ++c) {
                f32x2 v = __builtin_nontemporal_load(src + c);
                s0 = fmaf(v.x, w[2*c], s0); s0 = fmaf(v.y, w[2*c+1], s0);
            }
            acc += fmaxf(s0, 0.f);
        }
        if (lane < H) PA[(size_t)atom * H + lane] = acc;
    }
}

// ================= stage 2 (fat, 512 threads): pair_out (MFMA) || atom_out =================
// 8 waves/block, 33 KB LDS -> 4 blocks/CU = 32 waves/CU (full wave occupancy).
// Per-block weight staging (20.2 KB) amortized over 2x the waves of the 256-thread variant.
__global__ __launch_bounds__(512, 8) void k_stage2(
    const float* __restrict__ pf, const int* __restrict__ a2p,
    const unsigned short* __restrict__ X,
    const float* __restrict__ W_PP, const float* __restrict__ b_PP,
    const float* __restrict__ W_P, const float* __restrict__ b_P,
    const float* __restrict__ AA, const float* __restrict__ PA,
    const float* __restrict__ W_A, const float* __restrict__ b_A,
    float* __restrict__ outA, float* __restrict__ outP)
{
    __shared__ __align__(16) char smem[33024];

    const int tid  = threadIdx.x;
    const int wave = __builtin_amdgcn_readfirstlane(tid >> 6);
    const int lane = tid & 63;

    if (blockIdx.x < PO_BLOCKS) {
        uint4* sWf = (uint4*)smem;                                // 16 KB
        float (*sWPP)[64] = (float(*)[64])(smem + 16384);         // 3.5 KB
        float* sbPP = (float*)(smem + 16384 + 3584);              // 256 B
        float* sT   = (float*)(smem + 16384 + 3584 + 256);        // 8*400*4 = 12.8 KB

        // build B-frags (R3-validated): lane holds col=lane&15, k = s*32+(lane>>4)*8+[0..7]
        #pragma unroll
        for (int r = 0; r < 2; ++r) {
            int e = r * 512 + tid;                // 1024 entries total
            int fid = e >> 6, lane_e = e & 63;
            int s_ = fid >> 2, n_ = fid & 3;
            int col_e = lane_e & 15, gg = lane_e >> 4;
            int k0 = s_ * 32 + gg * 8;
            int c = n_ * 16 + col_e;
            unsigned w[4];
            #pragma unroll
            for (int hh = 0; hh < 4; ++hh) {
                float vlo = 0.f, vhi = 0.f;
                if (c < H) {
                    int k = k0 + 2 * hh;
                    int r0 = (k < 64) ? (k < H ? k : -1) : ((k - 64) < H ? H + (k - 64) : -1);
                    int k2 = k + 1;
                    int r1 = (k2 < 64) ? (k2 < H ? k2 : -1) : ((k2 - 64) < H ? H + (k2 - 64) : -1);
                    if (r0 >= 0) vlo = W_P[r0 * H + c];
                    if (r1 >= 0) vhi = W_P[r1 * H + c];
                }
                w[hh] = (unsigned)f2bf(vlo) | ((unsigned)f2bf(vhi) << 16);
            }
            sWf[e] = make_uint4(w[0], w[1], w[2], w[3]);
        }
        for (int t = tid; t < F_P * 64; t += 512) {
            int c = t >> 6, o = t & 63;
            sWPP[c][o] = (o < H) ? W_PP[c * H + o] : 0.f;
        }
        if (tid < 64) sbPP[tid] = tid < H ? b_PP[tid] : 0.f;
        __syncthreads();

        const int col = lane & 15;
        const int g = lane >> 4;
        float* const myT = sT + wave * 400;

        float bP[4];
        #pragma unroll
        for (int n = 0; n < 4; ++n) {
            int c = n * 16 + col;
            bP[n] = (c < H) ? b_P[c] : 0.f;
        }

        const int NT = N_PAIRS / 16;     // 100000 tiles
        const int step = PO_BLOCKS * 8;  // 8192 wave-slots (same as 256-thread variant)

        int t = blockIdx.x * 8 + wave;   // always < step <= NT
        int2 ij = ((const int2*)a2p)[t * 16 + col];
        while (t < NT) {
            const int t1 = t + step;
            int2 ij1 = ij;
            if (t1 < NT) ij1 = ((const int2*)a2p)[t1 * 16 + col];  // prefetch next tile's indices

            const int pairbase = t * 16;
            const unsigned short* Xi = X + (size_t)ij.x * 128;
            const unsigned short* Xj = X + (size_t)ij.y * 128;

            // issue all 8 gathers early (each 16B, lane owns its frag chunk)
            uint4 A1[2], B2[2], B1[2], A2[2];
            #pragma unroll
            for (int s = 0; s < 2; ++s) {
                int off = s * 32 + g * 8;
                A1[s] = *(const uint4*)(Xi + off);
                B2[s] = *(const uint4*)(Xj + 64 + off);
                B1[s] = *(const uint4*)(Xj + off);
                A2[s] = *(const uint4*)(Xi + 64 + off);
            }

            float pfr[F_P];
            {
                const f32x2* src = (const f32x2*)(pf + (size_t)(pairbase + col) * F_P);
                #pragma unroll
                for (int c = 0; c < 7; ++c) {
                    f32x2 v = __builtin_nontemporal_load(src + c);
                    pfr[2*c] = v.x; pfr[2*c+1] = v.y;
                }
            }

            f32x4 acc[4];
            #pragma unroll
            for (int n = 0; n < 4; ++n) acc[n] = (f32x4){bP[n], bP[n], bP[n], bP[n]};

            // ---- PP K-steps (global k = 64..127): overlaps gather latency ----
            #pragma unroll
            for (int s2 = 0; s2 < 2; ++s2) {
                int ob = s2 * 32 + g * 8;
                float pp[8];
                {
                    const f32x4* bb = (const f32x4*)&sbPP[ob];
                    f32x4 b0 = bb[0], b1 = bb[1];
                    pp[0]=b0.x; pp[1]=b0.y; pp[2]=b0.z; pp[3]=b0.w;
                    pp[4]=b1.x; pp[5]=b1.y; pp[6]=b1.z; pp[7]=b1.w;
                }
                #pragma unroll
                for (int c = 0; c < F_P; ++c) {
                    const f32x4* wr = (const f32x4*)&sWPP[c][ob];
                    f32x4 w0 = wr[0], w1 = wr[1];
                    float pc = pfr[c];
                    pp[0]=fmaf(pc,w0.x,pp[0]); pp[1]=fmaf(pc,w0.y,pp[1]);
                    pp[2]=fmaf(pc,w0.z,pp[2]); pp[3]=fmaf(pc,w0.w,pp[3]);
                    pp[4]=fmaf(pc,w1.x,pp[4]); pp[5]=fmaf(pc,w1.y,pp[5]);
                    pp[6]=fmaf(pc,w1.z,pp[6]); pp[7]=fmaf(pc,w1.w,pp[7]);
                }
                union { unsigned u[4]; bf16x8 v; } ap;
                #pragma unroll
                for (int hh = 0; hh < 4; ++hh) {
                    float lo = fmaxf(pp[2*hh], 0.f), hi2 = fmaxf(pp[2*hh+1], 0.f);
                    ap.u[hh] = (unsigned)f2bf(lo) | ((unsigned)f2bf(hi2) << 16);
                }
                int sg = 2 + s2;
                #pragma unroll
                for (int n = 0; n < 4; ++n) {
                    bf16x8 bfr = ((const bf16x8*)sWf)[(sg * 4 + n) * 64 + lane];
                    acc[n] = __builtin_amdgcn_mfma_f32_16x16x32_bf16(ap.v, bfr, acc[n], 0, 0, 0);
                }
            }

            // ---- AP K-steps (global k = 0..63); b_AP pre-folded into X1 ----
            #pragma unroll
            for (int s = 0; s < 2; ++s) {
                const unsigned* a1 = (const unsigned*)&A1[s];
                const unsigned* b2 = (const unsigned*)&B2[s];
                const unsigned* b1 = (const unsigned*)&B1[s];
                const unsigned* a2 = (const unsigned*)&A2[s];
                union { unsigned u[4]; bf16x8 v; } ap;
                #pragma unroll
                for (int hh = 0; hh < 4; ++hh) {
                    float e1l = bfu(a1[hh],0) + bfu(b2[hh],0);
                    float e2l = bfu(b1[hh],0) + bfu(a2[hh],0);
                    float apl = fmaxf(e1l, 0.f) + fmaxf(e2l, 0.f);
                    float e1h = bfu(a1[hh],1) + bfu(b2[hh],1);
                    float e2h = bfu(b1[hh],1) + bfu(a2[hh],1);
                    float aph = fmaxf(e1h, 0.f) + fmaxf(e2h, 0.f);
                    ap.u[hh] = (unsigned)f2bf(apl) | ((unsigned)f2bf(aph) << 16);
                }
                #pragma unroll
                for (int n = 0; n < 4; ++n) {
                    bf16x8 bfr = ((const bf16x8*)sWf)[(s * 4 + n) * 64 + lane];
                    acc[n] = __builtin_amdgcn_mfma_f32_16x16x32_bf16(ap.v, bfr, acc[n], 0, 0, 0);
                }
            }

            // ---- two-phase epilogue: rows 0..7 then 8..15 via 400-float wave buffer ----
            float* dst = outP + (size_t)pairbase * H;
            if (g < 2) {
                #pragma unroll
                for (int n = 0; n < 4; ++n) {
                    int c = n * 16 + col;
                    if (c < H) {
                        #pragma unroll
                        for (int q = 0; q < 4; ++q)
                            myT[(g * 4 + q) * H + c] = fmaxf(acc[n][q], 0.f);
                    }
                }
            }
            #pragma unroll
            for (int e = 0; e < 4; ++e) {
                int idx = e * 64 + lane;            // f32x2 idx, 200 total
                if (idx < 200) {
                    f32x2 v = *(const f32x2*)&myT[idx * 2];
                    *(f32x2*)(dst + idx * 2) = v;
                }
            }
            if (g >= 2) {
                #pragma unroll
                for (int n = 0; n < 4; ++n) {
                    int c = n * 16 + col;
                    if (c < H) {
                        #pragma unroll
                        for (int q = 0; q < 4; ++q)
                            myT[((g - 2) * 4 + q) * H + c] = fmaxf(acc[n][q], 0.f);
                    }
                }
            }
            #pragma unroll
            for (int e = 0; e < 4; ++e) {
                int idx = e * 64 + lane;
                if (idx < 200) {
                    f32x2 v = *(const f32x2*)&myT[idx * 2];
                    *(f32x2*)(dst + 400 + idx * 2) = v;
                }
            }

            ij = ij1;
            t = t1;
        }
    } else {
        // ---------------- atom_out (64 atoms/block, guarded tail) ----------------
        float* sW = (float*)smem;            // 20 KB
        float* sb = (float*)(smem + 20000);  // 200 B
        for (int t = tid; t < 2 * H * H; t += 512) sW[t] = W_A[t];
        if (tid < H) sb[tid] = b_A[tid];
        __syncthreads();

        const int h = lane < H ? lane : 0;
        const int base = (blockIdx.x - PO_BLOCKS) * 64 + wave * 8;

        float acc[8];
        #pragma unroll
        for (int a = 0; a < 8; ++a) acc[a] = sb[h];

        for (int k = 0; k < H; ++k) {
            float wA = sW[k * H + h];
            float wP = sW[(H + k) * H + h];
            #pragma unroll
            for (int a = 0; a < 8; ++a) {
                // loads beyond N_ATOMS stay inside the workspace (PA/row_start) — safe, discarded
                acc[a] = fmaf(AA[(size_t)(base + a) * H + k], wA, acc[a]);
                acc[a] = fmaf(PA[(size_t)(base + a) * H + k], wP, acc[a]);
            }
        }
        #pragma unroll
        for (int a = 0; a < 8; ++a) {
            int atom = base + a;
            if (atom < N_ATOMS && lane < H)
                outA[(size_t)atom * H + lane] = fmaxf(acc[a], 0.f);
        }
    }
}

// ---------------- launcher ----------------
extern "C" void kernel_launch(void* const* d_in, const int* in_sizes, int n_in,
                              void* d_out, int out_size, void* d_ws, size_t ws_size,
                              hipStream_t stream) {
    const float* af    = (const float*)d_in[0];
    const float* pfeat = (const float*)d_in[1];
    const int*   split = (const int*)d_in[2];
    const int*   a2p   = (const int*)d_in[3];
    const float* W_AA  = (const float*)d_in[4];
    const float* b_AA  = (const float*)d_in[5];
    const float* W_PA  = (const float*)d_in[6];
    const float* b_PA  = (const float*)d_in[7];
    const float* W_A   = (const float*)d_in[8];
    const float* b_A   = (const float*)d_in[9];
    const float* W_AP  = (const float*)d_in[10];
    const float* b_AP  = (const float*)d_in[11];
    const float* W_PP  = (const float*)d_in[12];
    const float* b_PP  = (const float*)d_in[13];
    const float* W_P   = (const float*)d_in[14];
    const float* b_P   = (const float*)d_in[15];

    float* outA = (float*)d_out;
    float* outP = (float*)d_out + (size_t)N_ATOMS * H;

    unsigned short* X  = (unsigned short*)d_ws;               // 25.6 MB
    float* AA          = (float*)(X + (size_t)N_ATOMS * 128); // 20 MB
    float* PA          = AA + (size_t)N_ATOMS * H;            // 20 MB
    int*   row_start   = (int*)(PA + (size_t)N_ATOMS * H);    // (N_ATOMS+1)*4B

    k_row_starts<<<(N_PAIRS + 255) / 256, 256, 0, stream>>>(split, row_start);
    k_stage1<<<PROJ_BLOCKS + SEG_BLOCKS, 256, 0, stream>>>(
        af, W_AA, b_AA, W_AP, b_AP, pfeat, row_start, W_PA, b_PA, AA, X, PA);
    k_stage2<<<PO_BLOCKS + AOUT_BLOCKS, 512, 0, stream>>>(
        pfeat, a2p, X, W_PP, b_PP, W_P, b_P, AA, PA, W_A, b_A, outA, outP);
}

// Round 18
// 451.367 us; speedup vs baseline: 1.5083x; 1.5083x over previous
//
#include <hip/hip_runtime.h>

#define N_ATOMS 100000
#define N_PAIRS 1600000
#define F_A 75
#define F_P 14
#define H 50

#define PROJ_BLOCKS (N_ATOMS / 32)       // 3125
#define RS_BLOCKS   ((N_PAIRS + 255) / 256) // 6250
#define SEG_BLOCKS  (N_ATOMS / 4)        // 25000
#define PO_BLOCKS   2048
#define AOUT_BLOCKS (N_ATOMS / 32)       // 3125

typedef float f32x2 __attribute__((ext_vector_type(2)));
typedef float f32x4 __attribute__((ext_vector_type(4)));
typedef short bf16x8 __attribute__((ext_vector_type(8)));

__device__ inline unsigned short f2bf(float f) {
    unsigned u = __float_as_uint(f);
    u += 0x7fffu + ((u >> 16) & 1u);
    return (unsigned short)(u >> 16);
}
__device__ inline float bfu(unsigned u, int hi) {
    return __uint_as_float(hi ? (u & 0xffff0000u) : (u << 16));
}

// ================= stage A (fat): atom_proj || row_starts =================
// pair_out only needs X (proj); segsum needs row_start. Both produced here in ~25us.
__global__ __launch_bounds__(256) void k_stageA(
    const float* __restrict__ af, const float* __restrict__ W_AA,
    const float* __restrict__ b_AA, const float* __restrict__ W_AP,
    const float* __restrict__ b_AP, const int* __restrict__ split,
    float* __restrict__ AA, unsigned short* __restrict__ X,
    int* __restrict__ row_start)
{
    const int wave = __builtin_amdgcn_readfirstlane(threadIdx.x >> 6);
    const int lane = threadIdx.x & 63;
    const int h = lane < H ? lane : 0;

    if (blockIdx.x < PROJ_BLOCKS) {
        const int base = blockIdx.x * 32 + wave * 8;
        const float bAA = b_AA[h];
        const float bAP = (lane < H) ? b_AP[lane] : 0.f;

        float aa[8], x1[8], x2[8];
        #pragma unroll
        for (int a = 0; a < 8; ++a) { aa[a] = bAA; x1[a] = 0.f; x2[a] = 0.f; }

        for (int c0 = 0; c0 < 72; c0 += 4) {
            f32x4 fv[8];
            #pragma unroll
            for (int a = 0; a < 8; ++a)
                fv[a] = *(const f32x4*)(af + (size_t)(base + a) * F_A + c0);
            #pragma unroll
            for (int cc = 0; cc < 4; ++cc) {
                int c = c0 + cc;
                float waa = W_AA[c * H + h];
                float w1  = W_AP[c * H + h];
                float w2  = W_AP[(F_A + c) * H + h];
                #pragma unroll
                for (int a = 0; a < 8; ++a) {
                    float f = fv[a][cc];
                    aa[a] = fmaf(f, waa, aa[a]);
                    x1[a] = fmaf(f, w1, x1[a]);
                    x2[a] = fmaf(f, w2, x2[a]);
                }
            }
        }
        #pragma unroll
        for (int c = 72; c < F_A; ++c) {
            float waa = W_AA[c * H + h];
            float w1  = W_AP[c * H + h];
            float w2  = W_AP[(F_A + c) * H + h];
            #pragma unroll
            for (int a = 0; a < 8; ++a) {
                float f = af[(size_t)(base + a) * F_A + c];
                aa[a] = fmaf(f, waa, aa[a]);
                x1[a] = fmaf(f, w1, x1[a]);
                x2[a] = fmaf(f, w2, x2[a]);
            }
        }
        #pragma unroll
        for (int a = 0; a < 8; ++a) {
            int atom = base + a;
            if (lane < H) AA[(size_t)atom * H + lane] = fmaxf(aa[a], 0.f);
            unsigned short v1 = (lane < H) ? f2bf(x1[a] + bAP) : (unsigned short)0;
            unsigned short v2 = (lane < H) ? f2bf(x2[a]) : (unsigned short)0;
            unsigned short* Xrow = X + (size_t)atom * 128;
            Xrow[lane]      = v1;
            Xrow[64 + lane] = v2;
        }
    } else {
        // row_starts
        int p = (blockIdx.x - PROJ_BLOCKS) * 256 + threadIdx.x;
        if (p >= N_PAIRS) return;
        int s = split[p];
        int sp = (p == 0) ? -1 : split[p - 1];
        for (int a = sp + 1; a <= s; ++a) row_start[a] = p;
        if (p == N_PAIRS - 1)
            for (int a = s + 1; a <= N_ATOMS; ++a) row_start[a] = N_PAIRS;
    }
}

// ================= stage B (fat, 1:13 interleaved): pair_out (MFMA) || pa_segsum =================
// Role mapping interleaves 2048 long-running pair blocks among 25000 segsum blocks so
// both kinds co-reside on CUs (trailing-role split would serialize them).
__global__ __launch_bounds__(256, 5) void k_stageB(
    const float* __restrict__ pf, const int* __restrict__ a2p,
    const unsigned short* __restrict__ X,
    const float* __restrict__ W_PP, const float* __restrict__ b_PP,
    const float* __restrict__ W_P, const float* __restrict__ b_P,
    const int* __restrict__ row_start,
    const float* __restrict__ W_PA, const float* __restrict__ b_PA,
    float* __restrict__ PA, float* __restrict__ outP)
{
    __shared__ __align__(16) char smem[26624];

    const int tid  = threadIdx.x;
    const int wave = __builtin_amdgcn_readfirstlane(tid >> 6);
    const int lane = tid & 63;
    const int h = lane < H ? lane : 0;

    const int idx = blockIdx.x;
    const int q = idx / 13, r = idx % 13;
    const bool is_pair = (r == 0) && (q < PO_BLOCKS);

    if (is_pair) {
        const int pair_blk = q;
        uint4* sWf = (uint4*)smem;                                // 16 KB
        float (*sWPP)[64] = (float(*)[64])(smem + 16384);         // 3.5 KB
        float* sbPP = (float*)(smem + 16384 + 3584);              // 256 B
        float* sT   = (float*)(smem + 16384 + 3584 + 256);        // 6.4 KB

        // build B-frags (R3-validated): lane holds col=lane&15, k = s*32+(lane>>4)*8+[0..7]
        #pragma unroll
        for (int rr = 0; rr < 4; ++rr) {
            int e = rr * 256 + tid;
            int fid = e >> 6, lane_e = e & 63;
            int s_ = fid >> 2, n_ = fid & 3;
            int col_e = lane_e & 15, gg = lane_e >> 4;
            int k0 = s_ * 32 + gg * 8;
            int c = n_ * 16 + col_e;
            unsigned w[4];
            #pragma unroll
            for (int hh = 0; hh < 4; ++hh) {
                float vlo = 0.f, vhi = 0.f;
                if (c < H) {
                    int k = k0 + 2 * hh;
                    int r0 = (k < 64) ? (k < H ? k : -1) : ((k - 64) < H ? H + (k - 64) : -1);
                    int k2 = k + 1;
                    int r1 = (k2 < 64) ? (k2 < H ? k2 : -1) : ((k2 - 64) < H ? H + (k2 - 64) : -1);
                    if (r0 >= 0) vlo = W_P[r0 * H + c];
                    if (r1 >= 0) vhi = W_P[r1 * H + c];
                }
                w[hh] = (unsigned)f2bf(vlo) | ((unsigned)f2bf(vhi) << 16);
            }
            sWf[e] = make_uint4(w[0], w[1], w[2], w[3]);
        }
        for (int t = tid; t < F_P * 64; t += 256) {
            int c = t >> 6, o = t & 63;
            sWPP[c][o] = (o < H) ? W_PP[c * H + o] : 0.f;
        }
        if (tid < 64) sbPP[tid] = tid < H ? b_PP[tid] : 0.f;
        __syncthreads();

        const int col = lane & 15;
        const int g = lane >> 4;
        float* const myT = sT + wave * 400;

        float bP[4];
        #pragma unroll
        for (int n = 0; n < 4; ++n) {
            int c = n * 16 + col;
            bP[n] = (c < H) ? b_P[c] : 0.f;
        }

        const int NT = N_PAIRS / 16;     // 100000 tiles
        const int step = PO_BLOCKS * 4;  // 8192

        int t = pair_blk * 4 + wave;     // always < step <= NT
        int2 ij = ((const int2*)a2p)[t * 16 + col];
        while (t < NT) {
            const int t1 = t + step;
            int2 ij1 = ij;
            if (t1 < NT) ij1 = ((const int2*)a2p)[t1 * 16 + col];

            const int pairbase = t * 16;
            const unsigned short* Xi = X + (size_t)ij.x * 128;
            const unsigned short* Xj = X + (size_t)ij.y * 128;

            uint4 A1[2], B2[2], B1[2], A2[2];
            #pragma unroll
            for (int s = 0; s < 2; ++s) {
                int off = s * 32 + g * 8;
                A1[s] = *(const uint4*)(Xi + off);
                B2[s] = *(const uint4*)(Xj + 64 + off);
                B1[s] = *(const uint4*)(Xj + off);
                A2[s] = *(const uint4*)(Xi + 64 + off);
            }

            float pfr[F_P];
            {
                const f32x2* src = (const f32x2*)(pf + (size_t)(pairbase + col) * F_P);
                #pragma unroll
                for (int c = 0; c < 7; ++c) {
                    f32x2 v = __builtin_nontemporal_load(src + c);
                    pfr[2*c] = v.x; pfr[2*c+1] = v.y;
                }
            }

            f32x4 acc[4];
            #pragma unroll
            for (int n = 0; n < 4; ++n) acc[n] = (f32x4){bP[n], bP[n], bP[n], bP[n]};

            // ---- PP K-steps (global k = 64..127) ----
            #pragma unroll
            for (int s2 = 0; s2 < 2; ++s2) {
                int ob = s2 * 32 + g * 8;
                float pp[8];
                {
                    const f32x4* bb = (const f32x4*)&sbPP[ob];
                    f32x4 b0 = bb[0], b1 = bb[1];
                    pp[0]=b0.x; pp[1]=b0.y; pp[2]=b0.z; pp[3]=b0.w;
                    pp[4]=b1.x; pp[5]=b1.y; pp[6]=b1.z; pp[7]=b1.w;
                }
                #pragma unroll
                for (int c = 0; c < F_P; ++c) {
                    const f32x4* wr = (const f32x4*)&sWPP[c][ob];
                    f32x4 w0 = wr[0], w1 = wr[1];
                    float pc = pfr[c];
                    pp[0]=fmaf(pc,w0.x,pp[0]); pp[1]=fmaf(pc,w0.y,pp[1]);
                    pp[2]=fmaf(pc,w0.z,pp[2]); pp[3]=fmaf(pc,w0.w,pp[3]);
                    pp[4]=fmaf(pc,w1.x,pp[4]); pp[5]=fmaf(pc,w1.y,pp[5]);
                    pp[6]=fmaf(pc,w1.z,pp[6]); pp[7]=fmaf(pc,w1.w,pp[7]);
                }
                union { unsigned u[4]; bf16x8 v; } ap;
                #pragma unroll
                for (int hh = 0; hh < 4; ++hh) {
                    float lo = fmaxf(pp[2*hh], 0.f), hi2 = fmaxf(pp[2*hh+1], 0.f);
                    ap.u[hh] = (unsigned)f2bf(lo) | ((unsigned)f2bf(hi2) << 16);
                }
                int sg = 2 + s2;
                #pragma unroll
                for (int n = 0; n < 4; ++n) {
                    bf16x8 bfr = ((const bf16x8*)sWf)[(sg * 4 + n) * 64 + lane];
                    acc[n] = __builtin_amdgcn_mfma_f32_16x16x32_bf16(ap.v, bfr, acc[n], 0, 0, 0);
                }
            }

            // ---- AP K-steps (global k = 0..63); b_AP pre-folded into X1 ----
            #pragma unroll
            for (int s = 0; s < 2; ++s) {
                const unsigned* a1 = (const unsigned*)&A1[s];
                const unsigned* b2 = (const unsigned*)&B2[s];
                const unsigned* b1 = (const unsigned*)&B1[s];
                const unsigned* a2 = (const unsigned*)&A2[s];
                union { unsigned u[4]; bf16x8 v; } ap;
                #pragma unroll
                for (int hh = 0; hh < 4; ++hh) {
                    float e1l = bfu(a1[hh],0) + bfu(b2[hh],0);
                    float e2l = bfu(b1[hh],0) + bfu(a2[hh],0);
                    float apl = fmaxf(e1l, 0.f) + fmaxf(e2l, 0.f);
                    float e1h = bfu(a1[hh],1) + bfu(b2[hh],1);
                    float e2h = bfu(b1[hh],1) + bfu(a2[hh],1);
                    float aph = fmaxf(e1h, 0.f) + fmaxf(e2h, 0.f);
                    ap.u[hh] = (unsigned)f2bf(apl) | ((unsigned)f2bf(aph) << 16);
                }
                #pragma unroll
                for (int n = 0; n < 4; ++n) {
                    bf16x8 bfr = ((const bf16x8*)sWf)[(s * 4 + n) * 64 + lane];
                    acc[n] = __builtin_amdgcn_mfma_f32_16x16x32_bf16(ap.v, bfr, acc[n], 0, 0, 0);
                }
            }

            // ---- two-phase epilogue; nt stores (full-sector contiguous) keep outP out of L3
            //      so the X gather table stays resident ----
            float* dst = outP + (size_t)pairbase * H;
            if (g < 2) {
                #pragma unroll
                for (int n = 0; n < 4; ++n) {
                    int c = n * 16 + col;
                    if (c < H) {
                        #pragma unroll
                        for (int qq = 0; qq < 4; ++qq)
                            myT[(g * 4 + qq) * H + c] = fmaxf(acc[n][qq], 0.f);
                    }
                }
            }
            #pragma unroll
            for (int e = 0; e < 4; ++e) {
                int idx2 = e * 64 + lane;
                if (idx2 < 200) {
                    f32x2 v = *(const f32x2*)&myT[idx2 * 2];
                    __builtin_nontemporal_store(v, (f32x2*)(dst + idx2 * 2));
                }
            }
            if (g >= 2) {
                #pragma unroll
                for (int n = 0; n < 4; ++n) {
                    int c = n * 16 + col;
                    if (c < H) {
                        #pragma unroll
                        for (int qq = 0; qq < 4; ++qq)
                            myT[((g - 2) * 4 + qq) * H + c] = fmaxf(acc[n][qq], 0.f);
                    }
                }
            }
            #pragma unroll
            for (int e = 0; e < 4; ++e) {
                int idx2 = e * 64 + lane;
                if (idx2 < 200) {
                    f32x2 v = *(const f32x2*)&myT[idx2 * 2];
                    __builtin_nontemporal_store(v, (f32x2*)(dst + 400 + idx2 * 2));
                }
            }

            ij = ij1;
            t = t1;
        }
    } else {
        // ---------------- pa_segsum ----------------
        const int pairs_below = min(PO_BLOCKS, q + (r > 0 ? 1 : 0));
        const int seg_id = idx - pairs_below;          // 0..24999
        const int atom = seg_id * 4 + wave;

        float w[F_P];
        #pragma unroll
        for (int c = 0; c < F_P; ++c) w[c] = W_PA[c * H + h];
        const float bias = b_PA[h];

        const int start = row_start[atom];
        const int end   = row_start[atom + 1];

        float acc = 0.f;
        int p = start;
        for (; p + 4 <= end; p += 4) {
            f32x2 v[4][7];
            #pragma unroll
            for (int rr = 0; rr < 4; ++rr) {
                const f32x2* src = (const f32x2*)(pf + (size_t)(p + rr) * F_P);
                #pragma unroll
                for (int c = 0; c < 7; ++c) v[rr][c] = __builtin_nontemporal_load(src + c);
            }
            #pragma unroll
            for (int rr = 0; rr < 4; ++rr) {
                float s0 = bias;
                #pragma unroll
                for (int c = 0; c < 7; ++c) {
                    s0 = fmaf(v[rr][c].x, w[2*c], s0);
                    s0 = fmaf(v[rr][c].y, w[2*c+1], s0);
                }
                acc += fmaxf(s0, 0.f);
            }
        }
        for (; p < end; ++p) {
            const f32x2* src = (const f32x2*)(pf + (size_t)p * F_P);
            float s0 = bias;
            #pragma unroll
            for (int c = 0; c < 7; ++c) {
                f32x2 v = __builtin_nontemporal_load(src + c);
                s0 = fmaf(v.x, w[2*c], s0); s0 = fmaf(v.y, w[2*c+1], s0);
            }
            acc += fmaxf(s0, 0.f);
        }
        if (lane < H) PA[(size_t)atom * H + lane] = acc;
    }
}

// ================= stage C: atom_out =================
__global__ __launch_bounds__(256) void k_atom_out(
    const float* __restrict__ AA, const float* __restrict__ PA,
    const float* __restrict__ W_A, const float* __restrict__ b_A,
    float* __restrict__ outA)
{
    __shared__ float sW[2 * H * H];
    __shared__ float sb[H];
    for (int t = threadIdx.x; t < 2 * H * H; t += 256) sW[t] = W_A[t];
    if (threadIdx.x < H) sb[threadIdx.x] = b_A[threadIdx.x];
    __syncthreads();

    const int wave = __builtin_amdgcn_readfirstlane(threadIdx.x >> 6);
    const int lane = threadIdx.x & 63;
    const int h = lane < H ? lane : 0;
    const int base = blockIdx.x * 32 + wave * 8;

    float acc[8];
    #pragma unroll
    for (int a = 0; a < 8; ++a) acc[a] = sb[h];

    for (int k = 0; k < H; ++k) {
        float wA = sW[k * H + h];
        float wP = sW[(H + k) * H + h];
        #pragma unroll
        for (int a = 0; a < 8; ++a) {
            acc[a] = fmaf(AA[(size_t)(base + a) * H + k], wA, acc[a]);
            acc[a] = fmaf(PA[(size_t)(base + a) * H + k], wP, acc[a]);
        }
    }
    #pragma unroll
    for (int a = 0; a < 8; ++a)
        if (lane < H) outA[(size_t)(base + a) * H + lane] = fmaxf(acc[a], 0.f);
}

// ---------------- launcher ----------------
extern "C" void kernel_launch(void* const* d_in, const int* in_sizes, int n_in,
                              void* d_out, int out_size, void* d_ws, size_t ws_size,
                              hipStream_t stream) {
    const float* af    = (const float*)d_in[0];
    const float* pfeat = (const float*)d_in[1];
    const int*   split = (const int*)d_in[2];
    const int*   a2p   = (const int*)d_in[3];
    const float* W_AA  = (const float*)d_in[4];
    const float* b_AA  = (const float*)d_in[5];
    const float* W_PA  = (const float*)d_in[6];
    const float* b_PA  = (const float*)d_in[7];
    const float* W_A   = (const float*)d_in[8];
    const float* b_A   = (const float*)d_in[9];
    const float* W_AP  = (const float*)d_in[10];
    const float* b_AP  = (const float*)d_in[11];
    const float* W_PP  = (const float*)d_in[12];
    const float* b_PP  = (const float*)d_in[13];
    const float* W_P   = (const float*)d_in[14];
    const float* b_P   = (const float*)d_in[15];

    float* outA = (float*)d_out;
    float* outP = (float*)d_out + (size_t)N_ATOMS * H;

    unsigned short* X  = (unsigned short*)d_ws;               // 25.6 MB
    float* AA          = (float*)(X + (size_t)N_ATOMS * 128); // 20 MB
    float* PA          = AA + (size_t)N_ATOMS * H;            // 20 MB
    int*   row_start   = (int*)(PA + (size_t)N_ATOMS * H);    // (N_ATOMS+1)*4B

    k_stageA<<<PROJ_BLOCKS + RS_BLOCKS, 256, 0, stream>>>(
        af, W_AA, b_AA, W_AP, b_AP, split, AA, X, row_start);
    k_stageB<<<PO_BLOCKS + SEG_BLOCKS, 256, 0, stream>>>(
        pfeat, a2p, X, W_PP, b_PP, W_P, b_P, row_start, W_PA, b_PA, PA, outP);
    k_atom_out<<<AOUT_BLOCKS, 256, 0, stream>>>(AA, PA, W_A, b_A, outA);
}

// Round 19
// 398.168 us; speedup vs baseline: 1.7099x; 1.1336x over previous
//
#include <hip/hip_runtime.h>

#define N_ATOMS 100000
#define N_PAIRS 1600000
#define F_A 75
#define F_P 14
#define H 50

#define PROJ_BLOCKS (N_ATOMS / 32)       // 3125
#define RS_BLOCKS   ((N_PAIRS + 255) / 256) // 6250
#define SEG_BLOCKS  (N_ATOMS / 4)        // 25000
#define PO_BLOCKS   2048

typedef float f32x2 __attribute__((ext_vector_type(2)));
typedef float f32x4 __attribute__((ext_vector_type(4)));
typedef short bf16x8 __attribute__((ext_vector_type(8)));

__device__ inline unsigned short f2bf(float f) {
    unsigned u = __float_as_uint(f);
    u += 0x7fffu + ((u >> 16) & 1u);
    return (unsigned short)(u >> 16);
}
__device__ inline float bfu(unsigned u, int hi) {
    return __uint_as_float(hi ? (u & 0xffff0000u) : (u << 16));
}

// ================= stage A (fat): atom_proj || row_starts =================
__global__ __launch_bounds__(256) void k_stageA(
    const float* __restrict__ af, const float* __restrict__ W_AA,
    const float* __restrict__ b_AA, const float* __restrict__ W_AP,
    const float* __restrict__ b_AP, const int* __restrict__ split,
    float* __restrict__ AA, unsigned short* __restrict__ X,
    int* __restrict__ row_start)
{
    const int wave = __builtin_amdgcn_readfirstlane(threadIdx.x >> 6);
    const int lane = threadIdx.x & 63;
    const int h = lane < H ? lane : 0;

    if (blockIdx.x < PROJ_BLOCKS) {
        const int base = blockIdx.x * 32 + wave * 8;
        const float bAA = b_AA[h];
        const float bAP = (lane < H) ? b_AP[lane] : 0.f;

        float aa[8], x1[8], x2[8];
        #pragma unroll
        for (int a = 0; a < 8; ++a) { aa[a] = bAA; x1[a] = 0.f; x2[a] = 0.f; }

        for (int c0 = 0; c0 < 72; c0 += 4) {
            f32x4 fv[8];
            #pragma unroll
            for (int a = 0; a < 8; ++a)
                fv[a] = *(const f32x4*)(af + (size_t)(base + a) * F_A + c0);
            #pragma unroll
            for (int cc = 0; cc < 4; ++cc) {
                int c = c0 + cc;
                float waa = W_AA[c * H + h];
                float w1  = W_AP[c * H + h];
                float w2  = W_AP[(F_A + c) * H + h];
                #pragma unroll
                for (int a = 0; a < 8; ++a) {
                    float f = fv[a][cc];
                    aa[a] = fmaf(f, waa, aa[a]);
                    x1[a] = fmaf(f, w1, x1[a]);
                    x2[a] = fmaf(f, w2, x2[a]);
                }
            }
        }
        #pragma unroll
        for (int c = 72; c < F_A; ++c) {
            float waa = W_AA[c * H + h];
            float w1  = W_AP[c * H + h];
            float w2  = W_AP[(F_A + c) * H + h];
            #pragma unroll
            for (int a = 0; a < 8; ++a) {
                float f = af[(size_t)(base + a) * F_A + c];
                aa[a] = fmaf(f, waa, aa[a]);
                x1[a] = fmaf(f, w1, x1[a]);
                x2[a] = fmaf(f, w2, x2[a]);
            }
        }
        #pragma unroll
        for (int a = 0; a < 8; ++a) {
            int atom = base + a;
            if (lane < H) AA[(size_t)atom * H + lane] = fmaxf(aa[a], 0.f);
            unsigned short v1 = (lane < H) ? f2bf(x1[a] + bAP) : (unsigned short)0;
            unsigned short v2 = (lane < H) ? f2bf(x2[a]) : (unsigned short)0;
            unsigned short* Xrow = X + (size_t)atom * 128;
            Xrow[lane]      = v1;
            Xrow[64 + lane] = v2;
        }
    } else {
        int p = (blockIdx.x - PROJ_BLOCKS) * 256 + threadIdx.x;
        if (p >= N_PAIRS) return;
        int s = split[p];
        int sp = (p == 0) ? -1 : split[p - 1];
        for (int a = sp + 1; a <= s; ++a) row_start[a] = p;
        if (p == N_PAIRS - 1)
            for (int a = s + 1; a <= N_ATOMS; ++a) row_start[a] = N_PAIRS;
    }
}

// ================= stage B (fat, 1:13 interleaved): pair_out (MFMA) || segsum+atom_out =================
// segsum role keeps PA[atom] in registers/LDS and applies W_A immediately -> writes A directly.
__global__ __launch_bounds__(256, 5) void k_stageB(
    const float* __restrict__ pf, const int* __restrict__ a2p,
    const unsigned short* __restrict__ X,
    const float* __restrict__ W_PP, const float* __restrict__ b_PP,
    const float* __restrict__ W_P, const float* __restrict__ b_P,
    const int* __restrict__ row_start,
    const float* __restrict__ W_PA, const float* __restrict__ b_PA,
    const float* __restrict__ AA, const float* __restrict__ W_A,
    const float* __restrict__ b_A,
    float* __restrict__ outA, float* __restrict__ outP)
{
    __shared__ __align__(16) char smem[26624];

    const int tid  = threadIdx.x;
    const int wave = __builtin_amdgcn_readfirstlane(tid >> 6);
    const int lane = tid & 63;
    const int h = lane < H ? lane : 0;

    const int idx = blockIdx.x;
    const int q = idx / 13, r = idx % 13;
    const bool is_pair = (r == 0) && (q < PO_BLOCKS);

    if (is_pair) {
        const int pair_blk = q;
        uint4* sWf = (uint4*)smem;                                // 16 KB
        float (*sWPP)[64] = (float(*)[64])(smem + 16384);         // 3.5 KB
        float* sbPP = (float*)(smem + 16384 + 3584);              // 256 B
        float* sT   = (float*)(smem + 16384 + 3584 + 256);        // 6.4 KB

        #pragma unroll
        for (int rr = 0; rr < 4; ++rr) {
            int e = rr * 256 + tid;
            int fid = e >> 6, lane_e = e & 63;
            int s_ = fid >> 2, n_ = fid & 3;
            int col_e = lane_e & 15, gg = lane_e >> 4;
            int k0 = s_ * 32 + gg * 8;
            int c = n_ * 16 + col_e;
            unsigned w[4];
            #pragma unroll
            for (int hh = 0; hh < 4; ++hh) {
                float vlo = 0.f, vhi = 0.f;
                if (c < H) {
                    int k = k0 + 2 * hh;
                    int r0 = (k < 64) ? (k < H ? k : -1) : ((k - 64) < H ? H + (k - 64) : -1);
                    int k2 = k + 1;
                    int r1 = (k2 < 64) ? (k2 < H ? k2 : -1) : ((k2 - 64) < H ? H + (k2 - 64) : -1);
                    if (r0 >= 0) vlo = W_P[r0 * H + c];
                    if (r1 >= 0) vhi = W_P[r1 * H + c];
                }
                w[hh] = (unsigned)f2bf(vlo) | ((unsigned)f2bf(vhi) << 16);
            }
            sWf[e] = make_uint4(w[0], w[1], w[2], w[3]);
        }
        for (int t = tid; t < F_P * 64; t += 256) {
            int c = t >> 6, o = t & 63;
            sWPP[c][o] = (o < H) ? W_PP[c * H + o] : 0.f;
        }
        if (tid < 64) sbPP[tid] = tid < H ? b_PP[tid] : 0.f;
        __syncthreads();

        const int col = lane & 15;
        const int g = lane >> 4;
        float* const myT = sT + wave * 400;

        float bP[4];
        #pragma unroll
        for (int n = 0; n < 4; ++n) {
            int c = n * 16 + col;
            bP[n] = (c < H) ? b_P[c] : 0.f;
        }

        const int NT = N_PAIRS / 16;
        const int step = PO_BLOCKS * 4;

        int t = pair_blk * 4 + wave;
        int2 ij = ((const int2*)a2p)[t * 16 + col];
        while (t < NT) {
            const int t1 = t + step;
            int2 ij1 = ij;
            if (t1 < NT) ij1 = ((const int2*)a2p)[t1 * 16 + col];

            const int pairbase = t * 16;
            const unsigned short* Xi = X + (size_t)ij.x * 128;
            const unsigned short* Xj = X + (size_t)ij.y * 128;

            uint4 A1[2], B2[2], B1[2], A2[2];
            #pragma unroll
            for (int s = 0; s < 2; ++s) {
                int off = s * 32 + g * 8;
                A1[s] = *(const uint4*)(Xi + off);
                B2[s] = *(const uint4*)(Xj + 64 + off);
                B1[s] = *(const uint4*)(Xj + off);
                A2[s] = *(const uint4*)(Xi + 64 + off);
            }

            float pfr[F_P];
            {
                const f32x2* src = (const f32x2*)(pf + (size_t)(pairbase + col) * F_P);
                #pragma unroll
                for (int c = 0; c < 7; ++c) {
                    f32x2 v = __builtin_nontemporal_load(src + c);
                    pfr[2*c] = v.x; pfr[2*c+1] = v.y;
                }
            }

            f32x4 acc[4];
            #pragma unroll
            for (int n = 0; n < 4; ++n) acc[n] = (f32x4){bP[n], bP[n], bP[n], bP[n]};

            // ---- PP K-steps (global k = 64..127) ----
            #pragma unroll
            for (int s2 = 0; s2 < 2; ++s2) {
                int ob = s2 * 32 + g * 8;
                float pp[8];
                {
                    const f32x4* bb = (const f32x4*)&sbPP[ob];
                    f32x4 b0 = bb[0], b1 = bb[1];
                    pp[0]=b0.x; pp[1]=b0.y; pp[2]=b0.z; pp[3]=b0.w;
                    pp[4]=b1.x; pp[5]=b1.y; pp[6]=b1.z; pp[7]=b1.w;
                }
                #pragma unroll
                for (int c = 0; c < F_P; ++c) {
                    const f32x4* wr = (const f32x4*)&sWPP[c][ob];
                    f32x4 w0 = wr[0], w1 = wr[1];
                    float pc = pfr[c];
                    pp[0]=fmaf(pc,w0.x,pp[0]); pp[1]=fmaf(pc,w0.y,pp[1]);
                    pp[2]=fmaf(pc,w0.z,pp[2]); pp[3]=fmaf(pc,w0.w,pp[3]);
                    pp[4]=fmaf(pc,w1.x,pp[4]); pp[5]=fmaf(pc,w1.y,pp[5]);
                    pp[6]=fmaf(pc,w1.z,pp[6]); pp[7]=fmaf(pc,w1.w,pp[7]);
                }
                union { unsigned u[4]; bf16x8 v; } ap;
                #pragma unroll
                for (int hh = 0; hh < 4; ++hh) {
                    float lo = fmaxf(pp[2*hh], 0.f), hi2 = fmaxf(pp[2*hh+1], 0.f);
                    ap.u[hh] = (unsigned)f2bf(lo) | ((unsigned)f2bf(hi2) << 16);
                }
                int sg = 2 + s2;
                #pragma unroll
                for (int n = 0; n < 4; ++n) {
                    bf16x8 bfr = ((const bf16x8*)sWf)[(sg * 4 + n) * 64 + lane];
                    acc[n] = __builtin_amdgcn_mfma_f32_16x16x32_bf16(ap.v, bfr, acc[n], 0, 0, 0);
                }
            }

            // ---- AP K-steps (global k = 0..63); b_AP pre-folded into X1 ----
            #pragma unroll
            for (int s = 0; s < 2; ++s) {
                const unsigned* a1 = (const unsigned*)&A1[s];
                const unsigned* b2 = (const unsigned*)&B2[s];
                const unsigned* b1 = (const unsigned*)&B1[s];
                const unsigned* a2 = (const unsigned*)&A2[s];
                union { unsigned u[4]; bf16x8 v; } ap;
                #pragma unroll
                for (int hh = 0; hh < 4; ++hh) {
                    float e1l = bfu(a1[hh],0) + bfu(b2[hh],0);
                    float e2l = bfu(b1[hh],0) + bfu(a2[hh],0);
                    float apl = fmaxf(e1l, 0.f) + fmaxf(e2l, 0.f);
                    float e1h = bfu(a1[hh],1) + bfu(b2[hh],1);
                    float e2h = bfu(b1[hh],1) + bfu(a2[hh],1);
                    float aph = fmaxf(e1h, 0.f) + fmaxf(e2h, 0.f);
                    ap.u[hh] = (unsigned)f2bf(apl) | ((unsigned)f2bf(aph) << 16);
                }
                #pragma unroll
                for (int n = 0; n < 4; ++n) {
                    bf16x8 bfr = ((const bf16x8*)sWf)[(s * 4 + n) * 64 + lane];
                    acc[n] = __builtin_amdgcn_mfma_f32_16x16x32_bf16(ap.v, bfr, acc[n], 0, 0, 0);
                }
            }

            // ---- two-phase epilogue; nt full-sector stores ----
            float* dst = outP + (size_t)pairbase * H;
            if (g < 2) {
                #pragma unroll
                for (int n = 0; n < 4; ++n) {
                    int c = n * 16 + col;
                    if (c < H) {
                        #pragma unroll
                        for (int qq = 0; qq < 4; ++qq)
                            myT[(g * 4 + qq) * H + c] = fmaxf(acc[n][qq], 0.f);
                    }
                }
            }
            #pragma unroll
            for (int e = 0; e < 4; ++e) {
                int idx2 = e * 64 + lane;
                if (idx2 < 200) {
                    f32x2 v = *(const f32x2*)&myT[idx2 * 2];
                    __builtin_nontemporal_store(v, (f32x2*)(dst + idx2 * 2));
                }
            }
            if (g >= 2) {
                #pragma unroll
                for (int n = 0; n < 4; ++n) {
                    int c = n * 16 + col;
                    if (c < H) {
                        #pragma unroll
                        for (int qq = 0; qq < 4; ++qq)
                            myT[((g - 2) * 4 + qq) * H + c] = fmaxf(acc[n][qq], 0.f);
                    }
                }
            }
            #pragma unroll
            for (int e = 0; e < 4; ++e) {
                int idx2 = e * 64 + lane;
                if (idx2 < 200) {
                    f32x2 v = *(const f32x2*)&myT[idx2 * 2];
                    __builtin_nontemporal_store(v, (f32x2*)(dst + 400 + idx2 * 2));
                }
            }

            ij = ij1;
            t = t1;
        }
    } else {
        // ---------------- segsum + fused atom_out ----------------
        float* sWA = (float*)smem;            // 20 KB: W_A [2H][H]
        float* pab = (float*)(smem + 20480);  // 4 waves x 64 floats = 1 KB
        for (int t2 = tid; t2 < 2 * H * H; t2 += 256) sWA[t2] = W_A[t2];
        __syncthreads();

        const int pairs_below = min(PO_BLOCKS, q + (r > 0 ? 1 : 0));
        const int seg_id = idx - pairs_below;          // 0..24999
        const int atom = seg_id * 4 + wave;

        float w[F_P];
        #pragma unroll
        for (int c = 0; c < F_P; ++c) w[c] = W_PA[c * H + h];
        const float bias = b_PA[h];

        const int start = row_start[atom];
        const int end   = row_start[atom + 1];

        float acc = 0.f;
        int p = start;
        for (; p + 4 <= end; p += 4) {
            f32x2 v[4][7];
            #pragma unroll
            for (int rr = 0; rr < 4; ++rr) {
                const f32x2* src = (const f32x2*)(pf + (size_t)(p + rr) * F_P);
                #pragma unroll
                for (int c = 0; c < 7; ++c) v[rr][c] = __builtin_nontemporal_load(src + c);
            }
            #pragma unroll
            for (int rr = 0; rr < 4; ++rr) {
                float s0 = bias;
                #pragma unroll
                for (int c = 0; c < 7; ++c) {
                    s0 = fmaf(v[rr][c].x, w[2*c], s0);
                    s0 = fmaf(v[rr][c].y, w[2*c+1], s0);
                }
                acc += fmaxf(s0, 0.f);
            }
        }
        for (; p < end; ++p) {
            const f32x2* src = (const f32x2*)(pf + (size_t)p * F_P);
            float s0 = bias;
            #pragma unroll
            for (int c = 0; c < 7; ++c) {
                f32x2 v = __builtin_nontemporal_load(src + c);
                s0 = fmaf(v.x, w[2*c], s0); s0 = fmaf(v.y, w[2*c+1], s0);
            }
            acc += fmaxf(s0, 0.f);
        }

        // PA[atom] lives in `acc` (lane<H). Round-trip through per-wave LDS slice
        // (same-wave RAW -> compiler lgkmcnt, no barrier) and apply W_A now.
        pab[wave * 64 + lane] = (lane < H) ? acc : 0.f;

        float accA = (lane < H) ? b_A[lane] : 0.f;
        const float* AArow = AA + (size_t)atom * H;
        for (int k = 0; k < H; ++k) {
            float aak = AArow[k];                       // wave-uniform -> scalar load
            accA = fmaf(aak, sWA[k * H + h], accA);
            accA = fmaf(pab[wave * 64 + k], sWA[(H + k) * H + h], accA);
        }
        if (lane < H) outA[(size_t)atom * H + lane] = fmaxf(accA, 0.f);
    }
}

// ---------------- launcher ----------------
extern "C" void kernel_launch(void* const* d_in, const int* in_sizes, int n_in,
                              void* d_out, int out_size, void* d_ws, size_t ws_size,
                              hipStream_t stream) {
    const float* af    = (const float*)d_in[0];
    const float* pfeat = (const float*)d_in[1];
    const int*   split = (const int*)d_in[2];
    const int*   a2p   = (const int*)d_in[3];
    const float* W_AA  = (const float*)d_in[4];
    const float* b_AA  = (const float*)d_in[5];
    const float* W_PA  = (const float*)d_in[6];
    const float* b_PA  = (const float*)d_in[7];
    const float* W_A   = (const float*)d_in[8];
    const float* b_A   = (const float*)d_in[9];
    const float* W_AP  = (const float*)d_in[10];
    const float* b_AP  = (const float*)d_in[11];
    const float* W_PP  = (const float*)d_in[12];
    const float* b_PP  = (const float*)d_in[13];
    const float* W_P   = (const float*)d_in[14];
    const float* b_P   = (const float*)d_in[15];

    float* outA = (float*)d_out;
    float* outP = (float*)d_out + (size_t)N_ATOMS * H;

    unsigned short* X  = (unsigned short*)d_ws;               // 25.6 MB
    float* AA          = (float*)(X + (size_t)N_ATOMS * 128); // 20 MB
    int*   row_start   = (int*)(AA + (size_t)N_ATOMS * H);    // (N_ATOMS+1)*4B

    k_stageA<<<PROJ_BLOCKS + RS_BLOCKS, 256, 0, stream>>>(
        af, W_AA, b_AA, W_AP, b_AP, split, AA, X, row_start);
    k_stageB<<<PO_BLOCKS + SEG_BLOCKS, 256, 0, stream>>>(
        pfeat, a2p, X, W_PP, b_PP, W_P, b_P, row_start, W_PA, b_PA,
        AA, W_A, b_A, outA, outP);
}